// Round 4
// baseline (1265.479 us; speedup 1.0000x reference)
//
#include <hip/hip_runtime.h>

#define T_STEPS 1024
#define BATCH 2048
#define HS 36    // Hb row stride in u32 words; 36 % 32 == 4 -> conflict-free b128 reads

typedef short short8 __attribute__((ext_vector_type(8)));
typedef float f32x4 __attribute__((ext_vector_type(4)));

__device__ __forceinline__ float rl(float v, int lane) {
    return __int_as_float(__builtin_amdgcn_readlane(__float_as_int(v), lane));
}

__device__ __forceinline__ float fast_rcp(float x) {
#if __has_builtin(__builtin_amdgcn_rcpf)
    return __builtin_amdgcn_rcpf(x);
#else
    return 1.0f / x;
#endif
}

__device__ __forceinline__ float fast_exp2(float x) {
#if __has_builtin(__builtin_amdgcn_exp2f)
    return __builtin_amdgcn_exp2f(x);
#else
    return exp2f(x);
#endif
}

__device__ __forceinline__ float sigf(float x) {
    return fast_rcp(1.0f + fast_exp2(-1.44269504f * x));
}

__device__ __forceinline__ float tanh_fast(float x) {
    float e = fast_exp2(2.88539008f * x);
    return 1.0f - 2.0f * fast_rcp(e + 1.0f);
}

// float -> bf16 bits (round-to-nearest-even)
__device__ __forceinline__ unsigned f2bf(float x) {
    unsigned u = __float_as_uint(x);
    unsigned r = u + 0x7FFFu + ((u >> 16) & 1u);
    return r >> 16;
}

__device__ __forceinline__ float dpp_add(float x, int which) {
    int xi = __float_as_int(x);
    int sh;
    switch (which) {
    case 0: sh = __builtin_amdgcn_update_dpp(0, xi, 0x111, 0xf, 0xf, true); break; // row_shr:1
    case 1: sh = __builtin_amdgcn_update_dpp(0, xi, 0x112, 0xf, 0xf, true); break; // row_shr:2
    case 2: sh = __builtin_amdgcn_update_dpp(0, xi, 0x114, 0xf, 0xf, true); break; // row_shr:4
    case 3: sh = __builtin_amdgcn_update_dpp(0, xi, 0x118, 0xf, 0xf, true); break; // row_shr:8
    case 4: sh = __builtin_amdgcn_update_dpp(0, xi, 0x142, 0xa, 0xf, true); break; // row_bcast:15
    default: sh = __builtin_amdgcn_update_dpp(0, xi, 0x143, 0xc, 0xf, true); break; // row_bcast:31
    }
    return x + __int_as_float(sh);
}

__device__ __forceinline__ float wave_allsum(float x) {
    x = dpp_add(x, 0);
    x = dpp_add(x, 1);
    x = dpp_add(x, 2);
    x = dpp_add(x, 3);
    x = dpp_add(x, 4);
    x = dpp_add(x, 5);
    return rl(x, 63);
}

// lane l receives lane l+1's value (within row of 16); only even lanes use it
__device__ __forceinline__ unsigned dpp_shl1(unsigned x) {
    return (unsigned)__builtin_amdgcn_update_dpp(0, (int)x, 0x101, 0xf, 0xf, true);
}

// One batch per WAVE, one wave per block (64 thr). The full W_hh0 (256x64)
// lives in this wave's registers as 16 M-tile A-fragments (128 VGPRs).
// Per step: G(256x16) = W . h^T via 32 MFMA (only batch col 0 used), gates
// round-trip a private LDS region, h round-trips LDS as bf16 pairs in exact
// B-fragment order. ALL data flow is within-wave -> NO __syncthreads in the
// loop; 8 independent waves/CU hide each other's LDS/exp latency.
// Layer-2 cell (fp32, DPP reduce) for step t-1 runs in step t's MFMA shadow.
__global__ __launch_bounds__(64, 2)
void lstm_wave_kernel(const float* __restrict__ input,
                      const float* __restrict__ W_ih0,
                      const float* __restrict__ W_hh0,
                      const float* __restrict__ b_ih0,
                      const float* __restrict__ b_hh0,
                      const float* __restrict__ W_ih1,
                      const float* __restrict__ W_hh1,
                      const float* __restrict__ b_ih1,
                      const float* __restrict__ b_hh1,
                      float* __restrict__ out)
{
    const int l = threadIdx.x;   // lane 0..63
    const int quad = l >> 4;
    const int n16 = l & 15;
    const int b = blockIdx.x;    // batch row

    __shared__ __align__(16) unsigned Hb[16][HS];  // bf16 pairs; rows 1..15 stay 0
    __shared__ __align__(16) float Gm[272];        // gates, row-major G[r], r=g*64+u

    #pragma unroll
    for (int idx = l; idx < 16 * HS; idx += 64)
        reinterpret_cast<unsigned*>(Hb)[idx] = 0u;

    // ---- persistent A fragments: afrag[i][kt] = W_hh0 tile (i, kt) ----
    // A[m=n16][k=8*quad+j], global row = 16i+n16, global k = 32*kt+8*quad+j
    short8 afrag[16][2];
    #pragma unroll
    for (int i = 0; i < 16; ++i) {
        const int row = 16 * i + n16;
        #pragma unroll
        for (int kt = 0; kt < 2; ++kt) {
            const float* p = W_hh0 + (size_t)row * 64 + kt * 32 + quad * 8;
            short8 a;
            #pragma unroll
            for (int j = 0; j < 8; ++j) a[j] = (short)f2bf(p[j]);
            afrag[i][kt] = a;
        }
    }

    // activation constants for unit l
    float wih0g[4], bias0g[4];
    #pragma unroll
    for (int g = 0; g < 4; ++g) {
        int r = g * 64 + l;
        wih0g[g] = W_ih0[r];
        bias0g[g] = b_ih0[r] + b_hh0[r];
    }
    // layer-2 constants
    float w1[4], whh1[4], b1s[4];
    #pragma unroll
    for (int g = 0; g < 4; ++g) {
        w1[g] = W_ih1[g * 64 + l];
        whh1[g] = W_hh1[g];
        b1s[g] = b_ih1[g] + b_hh1[g];
    }

    float c0 = 0.0f, h1 = 0.0f, c1 = 0.0f, c0n_prev = 0.0f;
    const float* inrow = input + (size_t)b * T_STEPS;
    float* outrow = out + (size_t)b * T_STEPS;

    float xcur = inrow[l];        // chunk 0
    float xnext = inrow[64 + l];  // chunk 1 prefetch

    __syncthreads();  // Hb zero visible (single wave; cheap)

    #pragma unroll 1
    for (int t = 0; t < T_STEPS; ++t) {
        if (t && (t & 63) == 0) {          // rotate x chunks, prefetch next
            xcur = xnext;
            int tn = (t + 64 <= T_STEPS - 64) ? t + 64 : T_STEPS - 64;
            xnext = inrow[tn + l];
        }

        // ---- B fragments: h(t-1) as bf16 pairs (rows>=1 are zero cols) ----
        short8 bf0 = *reinterpret_cast<const short8*>(&Hb[n16][4 * quad]);
        short8 bf1 = *reinterpret_cast<const short8*>(&Hb[n16][16 + 4 * quad]);

        // ---- 16 M-tiles: G[16i+4q+reg] in col 0; masked write (4 lanes) ----
        #pragma unroll
        for (int i = 0; i < 16; ++i) {
            f32x4 z = {0.0f, 0.0f, 0.0f, 0.0f};
            z = __builtin_amdgcn_mfma_f32_16x16x32_bf16(afrag[i][0], bf0, z, 0, 0, 0);
            z = __builtin_amdgcn_mfma_f32_16x16x32_bf16(afrag[i][1], bf1, z, 0, 0, 0);
            if (n16 == 0)
                *reinterpret_cast<f32x4*>(&Gm[16 * i + 4 * quad]) = z;
        }

        // issue gate reads (DS in-order: these follow the writes)
        float ga = Gm[l];
        float gb = Gm[64 + l];
        float gc = Gm[128 + l];
        float gd = Gm[192 + l];

        // ---- layer-2 cell for step t-1, in the MFMA/LDS shadow ----
        if (t > 0) {
            float s0 = wave_allsum(w1[0] * c0n_prev);
            float s1 = wave_allsum(w1[1] * c0n_prev);
            float s2 = wave_allsum(w1[2] * c0n_prev);
            float s3 = wave_allsum(w1[3] * c0n_prev);
            float g1i = s0 + b1s[0] + h1 * whh1[0];
            float g1f = s1 + b1s[1] + h1 * whh1[1];
            float g1g = s2 + b1s[2] + h1 * whh1[2];
            float g1o = s3 + b1s[3] + h1 * whh1[3];
            float c1n = sigf(g1f) * c1 + sigf(g1i) * tanh_fast(g1g);
            float h1n = sigf(g1o) * tanh_fast(c1n);
            c1 = c1n;
            h1 = h1n;
            if (l == 0) outrow[t - 1] = c1n;
        }

        // ---- layer-1 activation for unit l ----
        const float x = rl(xcur, t & 63);
        float gi = ga + fmaf(x, wih0g[0], bias0g[0]);
        float gf = gb + fmaf(x, wih0g[1], bias0g[1]);
        float gg = gc + fmaf(x, wih0g[2], bias0g[2]);
        float go = gd + fmaf(x, wih0g[3], bias0g[3]);

        float c0n = sigf(gf) * c0 + sigf(gi) * tanh_fast(gg);
        c0 = c0n;
        c0n_prev = c0n;
        float h0n = sigf(go) * tanh_fast(c0n);

        // pack h(t) as bf16 pairs; even lanes write one b32 (banks l/2: clean)
        unsigned own = f2bf(h0n);
        unsigned nb = dpp_shl1(own);
        if (!(l & 1)) Hb[0][l >> 1] = own | (nb << 16);
        // same-wave DS queue is in-order: next step's reads see this write
    }

    // epilogue: layer-2 for the last step
    {
        float s0 = wave_allsum(w1[0] * c0n_prev);
        float s1 = wave_allsum(w1[1] * c0n_prev);
        float s2 = wave_allsum(w1[2] * c0n_prev);
        float s3 = wave_allsum(w1[3] * c0n_prev);
        float g1i = s0 + b1s[0] + h1 * whh1[0];
        float g1f = s1 + b1s[1] + h1 * whh1[1];
        float g1g = s2 + b1s[2] + h1 * whh1[2];
        float g1o = s3 + b1s[3] + h1 * whh1[3];
        float c1n = sigf(g1f) * c1 + sigf(g1i) * tanh_fast(g1g);
        if (l == 0) outrow[T_STEPS - 1] = c1n;
    }
}

extern "C" void kernel_launch(void* const* d_in, const int* in_sizes, int n_in,
                              void* d_out, int out_size, void* d_ws, size_t ws_size,
                              hipStream_t stream) {
    const float* input = (const float*)d_in[0];
    const float* W_ih0 = (const float*)d_in[1];
    const float* W_hh0 = (const float*)d_in[2];
    const float* b_ih0 = (const float*)d_in[3];
    const float* b_hh0 = (const float*)d_in[4];
    const float* W_ih1 = (const float*)d_in[5];
    const float* W_hh1 = (const float*)d_in[6];
    const float* b_ih1 = (const float*)d_in[7];
    const float* b_hh1 = (const float*)d_in[8];
    float* out = (float*)d_out;

    dim3 grid(BATCH);   // 2048 single-wave blocks -> 8 blocks/CU, no barriers
    dim3 block(64);
    lstm_wave_kernel<<<grid, block, 0, stream>>>(
        input, W_ih0, W_hh0, b_ih0, b_hh0, W_ih1, W_hh1, b_ih1, b_hh1, out);
}

// Round 5
// 728.937 us; speedup vs baseline: 1.7361x; 1.7361x over previous
//
#include <hip/hip_runtime.h>

#define T_STEPS 1024
#define BATCH 2048
#define BTILE 4
#define HS 36   // LDS row stride in u32 words; 36 % 32 == 4 -> conflict-free b128 reads

typedef short short8 __attribute__((ext_vector_type(8)));
typedef float f32x4 __attribute__((ext_vector_type(4)));

__device__ __forceinline__ float fast_rcp(float x) {
#if __has_builtin(__builtin_amdgcn_rcpf)
    return __builtin_amdgcn_rcpf(x);
#else
    return 1.0f / x;
#endif
}

__device__ __forceinline__ float fast_exp2(float x) {
#if __has_builtin(__builtin_amdgcn_exp2f)
    return __builtin_amdgcn_exp2f(x);
#else
    return exp2f(x);
#endif
}

__device__ __forceinline__ float sigf(float x) {
    return fast_rcp(1.0f + fast_exp2(-1.44269504f * x));
}

__device__ __forceinline__ float tanh_fast(float x) {
    float e = fast_exp2(2.88539008f * x);
    return 1.0f - 2.0f * fast_rcp(e + 1.0f);
}

// float -> bf16 bits (round-to-nearest-even)
__device__ __forceinline__ unsigned f2bf(float x) {
    unsigned u = __float_as_uint(x);
    unsigned r = u + 0x7FFFu + ((u >> 16) & 1u);
    return r >> 16;
}
__device__ __forceinline__ float bf2f(unsigned b) {
    return __uint_as_float(b << 16);
}

// DPP lane moves (HW-validated conventions from R2-R4 passing runs):
// row_shl:N (0x100+N) -> lane receives lane l+N; row_shr:N (0x110+N) -> lane l-N
__device__ __forceinline__ float dpp_shr4f(float v) {
    return __int_as_float(__builtin_amdgcn_update_dpp(0, __float_as_int(v), 0x114, 0xf, 0xf, true));
}
__device__ __forceinline__ float dpp_shr8f(float v) {
    return __int_as_float(__builtin_amdgcn_update_dpp(0, __float_as_int(v), 0x118, 0xf, 0xf, true));
}
__device__ __forceinline__ float dpp_shr12f(float v) {
    return __int_as_float(__builtin_amdgcn_update_dpp(0, __float_as_int(v), 0x11C, 0xf, 0xf, true));
}
__device__ __forceinline__ unsigned dpp_shl4u(unsigned v) {
    return (unsigned)__builtin_amdgcn_update_dpp(0, (int)v, 0x104, 0xf, 0xf, true);
}

// R3-shape block (4 waves, 4 batches) with: interleaved M-tile ownership
// (wave w owns tiles {w,w+4,w+8,w+12} => holds ALL 4 gates of units
// 16w..16w+15 in its accumulators), in-register gate redistribution (DPP),
// ONE barrier per step (parity-double-buffered h/c0hi/c0lo LDS), and
// layer-2 as a hi/lo-split bf16 MFMA round-robined across waves.
__global__ __launch_bounds__(256, 2)
void lstm_v5_kernel(const float* __restrict__ input,
                    const float* __restrict__ W_ih0,
                    const float* __restrict__ W_hh0,
                    const float* __restrict__ b_ih0,
                    const float* __restrict__ b_hh0,
                    const float* __restrict__ W_ih1,
                    const float* __restrict__ W_hh1,
                    const float* __restrict__ b_ih1,
                    const float* __restrict__ b_hh1,
                    float* __restrict__ out)
{
    const int tid = threadIdx.x;
    const int w   = tid >> 6;        // wave id
    const int l   = tid & 63;        // lane
    const int q16 = l >> 4;          // quad-of-16
    const int n16 = l & 15;          // MFMA col (batch)
    const int nb  = l & 3;           // my batch (activation phase)
    const int r   = (l >> 2) & 3;    // my reg-row (activation phase)
    const int u   = 16 * w + 4 * q16 + r;   // my layer-1 unit
    const int bbase = blockIdx.x * BTILE;

    // [parity][h | c0hi | c0lo][batch-row][word]; rows 4..15 stay zero
    __shared__ __align__(16) unsigned Hbuf[2][3][16][HS];   // 13.8 KB
    __shared__ float Xb[2][BTILE][65];                      // x chunks, dbuf
    __shared__ float Lst[8];                                // h1[0..3], c1[4..7]

    for (int i = tid; i < 2 * 3 * 16 * HS; i += 256)
        reinterpret_cast<unsigned*>(Hbuf)[i] = 0u;
    if (tid < 8) Lst[tid] = 0.0f;

    // ---- L1 A-fragments: a1[g][kt] = W_hh0 tile (w+4g, kt) ----
    // A[m=n16][k=32kt+8q16+j], global row = 16(w+4g)+n16 = 64g + 16w + n16
    short8 a1[4][2];
    #pragma unroll
    for (int g = 0; g < 4; ++g) {
        #pragma unroll
        for (int kt = 0; kt < 2; ++kt) {
            const float* p = W_hh0 + (size_t)(16 * (w + 4 * g) + n16) * 64 + kt * 32 + q16 * 8;
            short8 a;
            #pragma unroll
            for (int j = 0; j < 8; ++j) a[j] = (short)f2bf(p[j]);
            a1[g][kt] = a;
        }
    }
    // ---- L2 A-fragments, hi/lo split; rows m>=4 are zero ----
    short8 a2h[2], a2l[2];
    #pragma unroll
    for (int kt = 0; kt < 2; ++kt) {
        short8 ah = {0,0,0,0,0,0,0,0}, al = {0,0,0,0,0,0,0,0};
        if (n16 < 4) {
            const float* p = W_ih1 + (size_t)n16 * 64 + kt * 32 + q16 * 8;
            #pragma unroll
            for (int j = 0; j < 8; ++j) {
                unsigned hb = f2bf(p[j]);
                ah[j] = (short)hb;
                al[j] = (short)f2bf(p[j] - bf2f(hb));
            }
        }
        a2h[kt] = ah; a2l[kt] = al;
    }

    // activation constants for cell (nb, u)
    float wg[4], bg[4];
    #pragma unroll
    for (int g = 0; g < 4; ++g) {
        int row = g * 64 + u;
        wg[g] = W_ih0[row];
        bg[g] = b_ih0[row] + b_hh0[row];
    }
    float whh1v[4], b1v[4];
    #pragma unroll
    for (int g = 0; g < 4; ++g) { whh1v[g] = W_hh1[g]; b1v[g] = b_ih1[g] + b_hh1[g]; }

    const float* inrow = input + (size_t)(bbase + w) * T_STEPS;
    Xb[0][w][l] = inrow[l];        // chunk 0
    float xnext = 0.0f;
    float c0 = 0.0f;

    __syncthreads();

    int par = 0;
    #pragma unroll 1
    for (int t = 0; t < T_STEPS; ++t) {
        if ((t & 63) == 0 && t + 64 < T_STEPS) xnext = inrow[t + 64 + l];
        const int cp = (t >> 6) & 1;

        // ---- B-fragments: h(t-1) ----
        const unsigned* Hrow = &Hbuf[par][0][n16][0];
        short8 hb0 = *reinterpret_cast<const short8*>(Hrow + 4 * q16);
        short8 hb1 = *reinterpret_cast<const short8*>(Hrow + 16 + 4 * q16);

        // ---- L1 MFMA: acc[g] = gate-g rows for units 16w..16w+15, all cols ----
        f32x4 accv[4];
        #pragma unroll
        for (int g = 0; g < 4; ++g) {
            f32x4 z = {0.0f, 0.0f, 0.0f, 0.0f};
            z = __builtin_amdgcn_mfma_f32_16x16x32_bf16(a1[g][0], hb0, z, 0, 0, 0);
            z = __builtin_amdgcn_mfma_f32_16x16x32_bf16(a1[g][1], hb1, z, 0, 0, 0);
            accv[g] = z;
        }

        // ---- layer-2 for step t-1 (round-robin wave), in the MFMA shadow ----
        if (t > 0 && w == ((t - 1) & 3)) {
            const unsigned* Ch = &Hbuf[par][1][n16][0];
            const unsigned* Cl = &Hbuf[par][2][n16][0];
            short8 ch0 = *reinterpret_cast<const short8*>(Ch + 4 * q16);
            short8 ch1 = *reinterpret_cast<const short8*>(Ch + 16 + 4 * q16);
            short8 cl0 = *reinterpret_cast<const short8*>(Cl + 4 * q16);
            short8 cl1 = *reinterpret_cast<const short8*>(Cl + 16 + 4 * q16);
            float h1p = Lst[nb], c1p = Lst[4 + nb];
            f32x4 z = {0.0f, 0.0f, 0.0f, 0.0f};
            z = __builtin_amdgcn_mfma_f32_16x16x32_bf16(a2h[0], ch0, z, 0, 0, 0);
            z = __builtin_amdgcn_mfma_f32_16x16x32_bf16(a2h[1], ch1, z, 0, 0, 0);
            z = __builtin_amdgcn_mfma_f32_16x16x32_bf16(a2l[0], ch0, z, 0, 0, 0);
            z = __builtin_amdgcn_mfma_f32_16x16x32_bf16(a2l[1], ch1, z, 0, 0, 0);
            z = __builtin_amdgcn_mfma_f32_16x16x32_bf16(a2h[0], cl0, z, 0, 0, 0);
            z = __builtin_amdgcn_mfma_f32_16x16x32_bf16(a2h[1], cl1, z, 0, 0, 0);
            // valid at lanes 0..15 (rows g = reg); only cols 0..3 real
            float g1i = z[0] + b1v[0] + h1p * whh1v[0];
            float g1f = z[1] + b1v[1] + h1p * whh1v[1];
            float g1g = z[2] + b1v[2] + h1p * whh1v[2];
            float g1o = z[3] + b1v[3] + h1p * whh1v[3];
            float c1n = sigf(g1f) * c1p + sigf(g1i) * tanh_fast(g1g);
            float h1n = sigf(g1o) * tanh_fast(c1n);
            if (l < 4) {
                out[(size_t)(bbase + l) * T_STEPS + (t - 1)] = c1n;
                Lst[l] = h1n;
                Lst[4 + l] = c1n;
            }
        }

        // ---- in-register gate redistribution: lane l <- accv[g][r] of lane l-4r ----
        float g4[4];
        #pragma unroll
        for (int g = 0; g < 4; ++g) {
            float v  = accv[g][0];
            float t1 = dpp_shr4f(accv[g][1]);
            float t2 = dpp_shr8f(accv[g][2]);
            float t3 = dpp_shr12f(accv[g][3]);
            v = (r == 1) ? t1 : v;
            v = (r == 2) ? t2 : v;
            v = (r == 3) ? t3 : v;
            g4[g] = v;
        }

        // ---- layer-1 activation for cell (nb, u) ----
        float x = Xb[cp][nb][t & 63];
        float gi = g4[0] + fmaf(x, wg[0], bg[0]);
        float gf = g4[1] + fmaf(x, wg[1], bg[1]);
        float gG = g4[2] + fmaf(x, wg[2], bg[2]);
        float go = g4[3] + fmaf(x, wg[3], bg[3]);
        float c0n = sigf(gf) * c0 + sigf(gi) * tanh_fast(gG);
        c0 = c0n;
        float h0n = sigf(go) * tanh_fast(c0n);

        // ---- pack h / c0hi / c0lo pairs, write to parity buffer ----
        unsigned hh  = f2bf(h0n);
        unsigned chi = f2bf(c0n);
        unsigned clo = f2bf(c0n - bf2f(chi));
        unsigned hhp  = dpp_shl4u(hh);    // partner unit u+1 (lane l+4)
        unsigned chip = dpp_shl4u(chi);
        unsigned clop = dpp_shl4u(clo);
        if (!(l & 4)) {                   // r even: owns pair (u, u+1)
            int widx = 8 * w + 2 * q16 + (r >> 1);
            Hbuf[par ^ 1][0][nb][widx] = hh  | (hhp  << 16);
            Hbuf[par ^ 1][1][nb][widx] = chi | (chip << 16);
            Hbuf[par ^ 1][2][nb][widx] = clo | (clop << 16);
        }
        if ((t & 63) == 63 && t + 1 < T_STEPS) Xb[cp ^ 1][w][l] = xnext;

        __syncthreads();
        par ^= 1;
    }

    // ---- epilogue: layer-2 for step 1023 (wave 3 = 1023 & 3) ----
    if (w == 3) {
        const unsigned* Ch = &Hbuf[par][1][n16][0];
        const unsigned* Cl = &Hbuf[par][2][n16][0];
        short8 ch0 = *reinterpret_cast<const short8*>(Ch + 4 * q16);
        short8 ch1 = *reinterpret_cast<const short8*>(Ch + 16 + 4 * q16);
        short8 cl0 = *reinterpret_cast<const short8*>(Cl + 4 * q16);
        short8 cl1 = *reinterpret_cast<const short8*>(Cl + 16 + 4 * q16);
        float h1p = Lst[nb], c1p = Lst[4 + nb];
        f32x4 z = {0.0f, 0.0f, 0.0f, 0.0f};
        z = __builtin_amdgcn_mfma_f32_16x16x32_bf16(a2h[0], ch0, z, 0, 0, 0);
        z = __builtin_amdgcn_mfma_f32_16x16x32_bf16(a2h[1], ch1, z, 0, 0, 0);
        z = __builtin_amdgcn_mfma_f32_16x16x32_bf16(a2l[0], ch0, z, 0, 0, 0);
        z = __builtin_amdgcn_mfma_f32_16x16x32_bf16(a2l[1], ch1, z, 0, 0, 0);
        z = __builtin_amdgcn_mfma_f32_16x16x32_bf16(a2h[0], cl0, z, 0, 0, 0);
        z = __builtin_amdgcn_mfma_f32_16x16x32_bf16(a2h[1], cl1, z, 0, 0, 0);
        float g1i = z[0] + b1v[0] + h1p * whh1v[0];
        float g1f = z[1] + b1v[1] + h1p * whh1v[1];
        float g1g = z[2] + b1v[2] + h1p * whh1v[2];
        float g1o = z[3] + b1v[3] + h1p * whh1v[3];
        float c1n = sigf(g1f) * c1p + sigf(g1i) * tanh_fast(g1g);
        if (l < 4)
            out[(size_t)(bbase + l) * T_STEPS + (T_STEPS - 1)] = c1n;
    }
}

extern "C" void kernel_launch(void* const* d_in, const int* in_sizes, int n_in,
                              void* d_out, int out_size, void* d_ws, size_t ws_size,
                              hipStream_t stream) {
    const float* input = (const float*)d_in[0];
    const float* W_ih0 = (const float*)d_in[1];
    const float* W_hh0 = (const float*)d_in[2];
    const float* b_ih0 = (const float*)d_in[3];
    const float* b_hh0 = (const float*)d_in[4];
    const float* W_ih1 = (const float*)d_in[5];
    const float* W_hh1 = (const float*)d_in[6];
    const float* b_ih1 = (const float*)d_in[7];
    const float* b_hh1 = (const float*)d_in[8];
    float* out = (float*)d_out;

    dim3 grid(BATCH / BTILE);   // 512 blocks -> 2 blocks/CU
    dim3 block(256);
    lstm_v5_kernel<<<grid, block, 0, stream>>>(
        input, W_ih0, W_hh0, b_ih0, b_hh0, W_ih1, W_hh1, b_ih1, b_hh1, out);
}